// Round 8
// baseline (332.840 us; speedup 1.0000x reference)
//
#include <hip/hip_runtime.h>

// Problem constants: B=16, NH=8, DH=64, NG=4, NC=512, CG=128, GH=2, H=W=32,
// HW=1024, Hs=Ws=16, NS=256, scale=0.125, ORF*off_range = 2/15.
// External buffers fp32; internal tensors bf16.

typedef __attribute__((ext_vector_type(8))) short short8;
typedef __attribute__((ext_vector_type(4))) float f32x4;

__device__ __forceinline__ float bf2f(ushort u) {
    union { uint i; float f; } c; c.i = ((uint)u) << 16; return c.f;
}
__device__ __forceinline__ ushort f2bf(float f) {
    union { float f; uint i; } c; c.f = f;
    uint x = c.i;
    return (ushort)((x + 0x7fffu + ((x >> 16) & 1u)) >> 16);  // RNE
}
__device__ __forceinline__ float sat(float v, float lim) {
    return fminf(fmaxf(v, -lim), lim);  // NaN-flushing clamp
}
__device__ __forceinline__ f32x4 mfma_bf16(short8 a, short8 b, f32x4 c) {
    return __builtin_amdgcn_mfma_f32_16x16x32_bf16(a, b, c, 0, 0, 0);
}

// ---------------------------------------------------------------------------
// One-time preps
__global__ __launch_bounds__(256) void prep_w(const float* __restrict__ w0,
                                              const float* __restrict__ w1,
                                              const float* __restrict__ w2,
                                              const float* __restrict__ w3,
                                              ushort* __restrict__ dst) {
    int widx = blockIdx.y;
    const float* src = widx == 0 ? w0 : widx == 1 ? w1 : widx == 2 ? w2 : w3;
    int i = blockIdx.x * 256 + threadIdx.x;
    float4 f = ((const float4*)src)[i];
    ushort4 u;
    u.x = f2bf(f.x); u.y = f2bf(f.y); u.z = f2bf(f.z); u.w = f2bf(f.w);
    ((ushort4*)(dst + (size_t)widx * 262144))[i] = u;
}

// rpe [8][63][63] fp32 -> padded bf16 [8][64][64] (row/col 63 zero)
__global__ __launch_bounds__(256) void prep_rpe(const float* __restrict__ rpe,
                                                ushort* __restrict__ tb8) {
    int h = blockIdx.x, t = threadIdx.x;
    for (int i = t; i < 4096; i += 256) {
        int yy = i >> 6, xx = i & 63;
        float v = (yy < 63 && xx < 63) ? rpe[(size_t)h * 3969 + yy * 63 + xx] : 0.f;
        tb8[(size_t)h * 4096 + i] = f2bf(v);
    }
}

// x [b][512][1024] fp32 -> xbT [bl][1024][512] bf16 (transpose+convert)
__global__ __launch_bounds__(256) void prep_xT(const float* __restrict__ x,
                                               ushort* __restrict__ xbT, int b0) {
    __shared__ float tile[64][33];
    int n0 = blockIdx.x * 32, c0 = blockIdx.y * 64, bl = blockIdx.z, bg = b0 + bl;
    int t = threadIdx.x;
#pragma unroll
    for (int it = 0; it < 8; it++) {
        int cr = it * 8 + (t >> 5), col = t & 31;
        tile[cr][col] = x[((size_t)bg * 512 + c0 + cr) * 1024 + n0 + col];
    }
    __syncthreads();
#pragma unroll
    for (int it = 0; it < 8; it++) {
        int nr = it * 4 + (t >> 6), cc = t & 63;
        xbT[((size_t)bl * 1024 + n0 + nr) * 512 + c0 + cc] = f2bf(tile[cc][nr]);
    }
}

// ---------------------------------------------------------------------------
// 128x128-tile GEMM: C[m][n] = sum_k A[m][k]*B[n][k] + bias[m]. A,B bf16.
// OUT_T=1: write C^T bf16 packed. OUT_T=0: row-major; CINT=1 bf16, CINT=0 fp32.
template <int OUT_T, int CINT>
__global__ __launch_bounds__(256) void gemm128(const ushort* __restrict__ A,
                                               const ushort* __restrict__ Bm,
                                               const float* __restrict__ bias,
                                               void* __restrict__ C, int K,
                                               size_t sB, size_t sC, int ldc, size_t c0) {
    __shared__ __align__(16) ushort As[128][72];
    __shared__ __align__(16) ushort Bs[128][72];
    int b = blockIdx.z, m0 = blockIdx.y * 128, n0 = blockIdx.x * 128;
    const ushort* Bp = Bm + (size_t)b * sB;
    size_t cb = c0 + (size_t)b * sC;
    int t = threadIdx.x, w = t >> 6, lane = t & 63, col = lane & 15, quad = lane >> 4;
    int m_off = (w & 1) * 64, n_off = (w >> 1) * 64;
    f32x4 acc[4][4] = {};
    for (int k0 = 0; k0 < K; k0 += 64) {
        __syncthreads();
        for (int i = t; i < 1024; i += 256) {
            int r = i >> 3, c8 = (i & 7) * 8;
            *(uint4*)&As[r][c8] = *(const uint4*)&A[(size_t)(m0 + r) * K + k0 + c8];
            *(uint4*)&Bs[r][c8] = *(const uint4*)&Bp[(size_t)(n0 + r) * K + k0 + c8];
        }
        __syncthreads();
#pragma unroll
        for (int kk = 0; kk < 2; kk++) {
            short8 af[4], bf[4];
#pragma unroll
            for (int mi = 0; mi < 4; mi++)
                af[mi] = *(const short8*)&As[m_off + mi * 16 + col][kk * 32 + quad * 8];
#pragma unroll
            for (int ni = 0; ni < 4; ni++)
                bf[ni] = *(const short8*)&Bs[n_off + ni * 16 + col][kk * 32 + quad * 8];
#pragma unroll
            for (int mi = 0; mi < 4; mi++)
#pragma unroll
                for (int ni = 0; ni < 4; ni++)
                    acc[mi][ni] = mfma_bf16(af[mi], bf[ni], acc[mi][ni]);
        }
    }
#pragma unroll
    for (int mi = 0; mi < 4; mi++)
#pragma unroll
        for (int ni = 0; ni < 4; ni++) {
            int mg = m0 + m_off + mi * 16 + quad * 4;
            int ng = n0 + n_off + ni * 16 + col;
            f32x4 vv = acc[mi][ni];
            if (OUT_T == 1) {
                ushort4 pk;
                pk.x = f2bf(sat(vv[0] + bias[mg + 0], 1e4f));
                pk.y = f2bf(sat(vv[1] + bias[mg + 1], 1e4f));
                pk.z = f2bf(sat(vv[2] + bias[mg + 2], 1e4f));
                pk.w = f2bf(sat(vv[3] + bias[mg + 3], 1e4f));
                *(ushort4*)&((ushort*)C)[cb + (size_t)ng * ldc + mg] = pk;
            } else {
#pragma unroll
                for (int r = 0; r < 4; r++) {
                    float v = sat(vv[r] + bias[mg + r], 1e4f);
                    if (CINT) ((ushort*)C)[cb + (size_t)(mg + r) * ldc + ng] = f2bf(v);
                    else ((float*)C)[cb + (size_t)(mg + r) * ldc + ng] = v;
                }
            }
        }
}

// ---------------------------------------------------------------------------
// Offset network: depthwise 3x3 s2 p1 -> LN(channel) -> GELU -> 1x1 -> tanh*2/15.
__global__ __launch_bounds__(128) void offset_net(
    const ushort* __restrict__ qT, const float* __restrict__ dww,
    const float* __restrict__ dwb, const float* __restrict__ lng,
    const float* __restrict__ lnb, const float* __restrict__ pww,
    float* __restrict__ pos, float* __restrict__ out, int b0) {
    int n = blockIdx.y, sp = blockIdx.x, bl = n >> 2, bg = b0 + bl, g = n & 3;
    int i = sp >> 4, j = sp & 15, c = threadIdx.x;
    float acc = dwb[c];
#pragma unroll
    for (int dy = 0; dy < 3; dy++) {
        int yy = 2 * i - 1 + dy;
        if (yy < 0 || yy > 31) continue;
#pragma unroll
        for (int dx = 0; dx < 3; dx++) {
            int xx = 2 * j - 1 + dx;
            if (xx < 0 || xx > 31) continue;
            acc += dww[c * 9 + dy * 3 + dx] *
                   bf2f(qT[((size_t)bl * 1024 + yy * 32 + xx) * 512 + g * 128 + c]);
        }
    }
    __shared__ float rs[128], rs2[128];
    rs[c] = acc; rs2[c] = acc * acc;
    __syncthreads();
    for (int s2 = 64; s2 > 0; s2 >>= 1) {
        if (c < s2) { rs[c] += rs[c + s2]; rs2[c] += rs2[c + s2]; }
        __syncthreads();
    }
    float mu = rs[0] * (1.f / 128.f);
    float var = rs2[0] * (1.f / 128.f) - mu * mu;
    float xn = (acc - mu) * rsqrtf(fmaxf(var, 0.f) + 1e-5f);
    float gl = xn * lng[c] + lnb[c];
    gl = 0.5f * gl * (1.f + erff(gl * 0.70710678118654752f));  // exact GELU
    __syncthreads();
    rs[c] = gl * pww[c];
    rs2[c] = gl * pww[128 + c];
    __syncthreads();
    for (int s2 = 64; s2 > 0; s2 >>= 1) {
        if (c < s2) { rs[c] += rs[c + s2]; rs2[c] += rs2[c + s2]; }
        __syncthreads();
    }
    if (c == 0) {
        float offy = tanhf(rs[0]) * (2.f / 15.f);
        float offx = tanhf(rs2[0]) * (2.f / 15.f);
        float ry = ((float)i + 0.5f) * (2.f / 15.f) - 1.f;
        float rx = ((float)j + 0.5f) * (2.f / 15.f) - 1.f;
        float py = sat(offy + ry, 1.2f), px = sat(offx + rx, 1.2f);
        size_t ol = ((size_t)(bl * 4 + g) * 256 + sp) * 2;   // chunk-local
        pos[ol] = py; pos[ol + 1] = px;
        size_t og = ((size_t)(bg * 4 + g) * 256 + sp) * 2;   // global out offset
        out[8388608 + og] = py;  out[8388608 + og + 1] = px;
        out[8421376 + og] = ry;  out[8421376 + og + 1] = rx;
    }
}

// ---------------------------------------------------------------------------
// Bilinear sample of x at pos -> xsT[bl][s][512] (bf16).
__global__ __launch_bounds__(128) void sample_x(const float* __restrict__ x,
                                                const float* __restrict__ pos,
                                                ushort* __restrict__ xsT, int b0) {
    int nl = blockIdx.y, s = blockIdx.x, bl = nl >> 2, bg = b0 + bl, g = nl & 3, c = threadIdx.x;
    size_t po = ((size_t)(bl * 4 + g) * 256 + s) * 2;
    float py = pos[po], px = pos[po + 1];
    float gx = (px + 1.f) * 15.5f;
    float gy = (py + 1.f) * 15.5f;
    float x0f = floorf(gx), y0f = floorf(gy);
    int ix0 = (int)x0f, iy0 = (int)y0f;
    float wx1 = gx - x0f, wx0 = 1.f - wx1, wy1 = gy - y0f, wy0 = 1.f - wy1;
    size_t xb = ((size_t)bg * 512 + g * 128 + c) * 1024;
    float acc = 0.f;
#define CORNER(ix, iy, wgt)                                            \
    if ((unsigned)(ix) < 32u && (unsigned)(iy) < 32u)                  \
        acc += (wgt) * x[xb + (iy) * 32 + (ix)];
    CORNER(ix0, iy0, wx0 * wy0)
    CORNER(ix0 + 1, iy0, wx1 * wy0)
    CORNER(ix0, iy0 + 1, wx0 * wy1)
    CORNER(ix0 + 1, iy0 + 1, wx1 * wy1)
#undef CORNER
    xsT[((size_t)bl * 256 + s) * 512 + g * 128 + c] = f2bf(sat(acc, 64.f));
}

// ---------------------------------------------------------------------------
// Fused attention v3: K staged in LDS (union with P), prepped bf16 rpe table,
// per-s bilinear weights, in-register softmax.
__global__ __launch_bounds__(256, 2) void fused_attn(const ushort* __restrict__ qT,
                                                     const ushort* __restrict__ kT,
                                                     const ushort* __restrict__ vS,
                                                     const ushort* __restrict__ tb8,
                                                     const float* __restrict__ pos,
                                                     ushort* __restrict__ outT) {
    __shared__ __align__(16) ushort KP[256 * 72];  // K phase: Ks[s][72]; P phase: Pl[m*264+s]
    __shared__ __align__(16) ushort Tb[4096];
    __shared__ float4 sW4[256];
    __shared__ int sIX[256], sIY[256];
    int bh = blockIdx.y, bl = bh >> 3, h = bh & 7, g = h >> 1;
    int m0 = blockIdx.x * 64;
    int t = threadIdx.x;
    {
        const ushort* kb = kT + (size_t)bl * 256 * 512 + h * 64;
        for (int i = t; i < 2048; i += 256) {
            int s = i >> 3, part = i & 7;
            *(uint4*)&KP[s * 72 + part * 8] = *(const uint4*)&kb[(size_t)s * 512 + part * 8];
        }
    }
    for (int i = t; i < 512; i += 256)
        ((uint4*)Tb)[i] = ((const uint4*)(tb8 + (size_t)h * 4096))[i];
    {
        int s = t;
        float psy = pos[(size_t)(bl * 4 + g) * 512 + 2 * s];
        float psx = pos[(size_t)(bl * 4 + g) * 512 + 2 * s + 1];
        float syf = 15.5f - 15.5f * psy;
        float sxf = 15.5f - 15.5f * psx;
        float fy = floorf(syf), fx = floorf(sxf);
        float wy1 = syf - fy, wy0 = 1.f - wy1;
        float wx1 = sxf - fx, wx0 = 1.f - wx1;
        sIY[s] = (int)fy; sIX[s] = (int)fx;
        sW4[s] = make_float4(wx0 * wy0, wx1 * wy0, wx0 * wy1, wx1 * wy1);
    }
    __syncthreads();
    int w = t >> 6, lane = t & 63, col = lane & 15, quad = lane >> 4;
    int mw = w * 16;
    const ushort* qrow = qT + ((size_t)bl * 1024 + m0 + mw + col) * 512 + h * 64;
    short8 a0 = *(const short8*)&qrow[quad * 8];
    short8 a1 = *(const short8*)&qrow[32 + quad * 8];
    f32x4 acc[16] = {};
#pragma unroll
    for (int ni = 0; ni < 16; ni++) {
        short8 b0v = *(const short8*)&KP[(ni * 16 + col) * 72 + quad * 8];
        short8 b1v = *(const short8*)&KP[(ni * 16 + col) * 72 + 32 + quad * 8];
        acc[ni] = mfma_bf16(a0, b0v, acc[ni]);
        acc[ni] = mfma_bf16(a1, b1v, acc[ni]);
    }
    int mbase = m0 + mw;
    int my = mbase >> 5;
    int mxq = (mbase & 31) + quad * 4;
#pragma unroll
    for (int ni = 0; ni < 16; ni++) {
        int s = ni * 16 + col;
        int p = mxq + sIX[s];
        int iy0 = my + sIY[s];
        float4 w4 = sW4[s];
        int ry0 = ((unsigned)iy0 < 63u) ? (iy0 << 6) : (63 << 6);
        int ry1 = ((unsigned)(iy0 + 1) < 63u) ? ((iy0 + 1) << 6) : (63 << 6);
        float t0[5], t1[5];
#pragma unroll
        for (int jj = 0; jj < 5; jj++) {
            int pj = p + jj;
            int cx = ((unsigned)pj < 63u) ? pj : 63;
            t0[jj] = bf2f(Tb[ry0 + cx]);
            t1[jj] = bf2f(Tb[ry1 + cx]);
        }
#pragma unroll
        for (int r = 0; r < 4; r++) {
            float bias = w4.x * t0[r] + w4.y * t0[r + 1] + w4.z * t1[r] + w4.w * t1[r + 1];
            acc[ni][r] = sat(acc[ni][r] * 0.125f + bias, 64.f);
        }
    }
    float rinv_[4];
#pragma unroll
    for (int r = 0; r < 4; r++) {
        float mr = acc[0][r];
#pragma unroll
        for (int ni = 1; ni < 16; ni++) mr = fmaxf(mr, acc[ni][r]);
#pragma unroll
        for (int off = 1; off < 16; off <<= 1) mr = fmaxf(mr, __shfl_xor(mr, off));
        float sr = 0.f;
#pragma unroll
        for (int ni = 0; ni < 16; ni++) {
            float e = __expf(acc[ni][r] - mr);
            acc[ni][r] = e;
            sr += e;
        }
#pragma unroll
        for (int off = 1; off < 16; off <<= 1) sr += __shfl_xor(sr, off);
        rinv_[r] = 1.f / sr;
    }
    __syncthreads();
#pragma unroll
    for (int ni = 0; ni < 16; ni++)
#pragma unroll
        for (int r = 0; r < 4; r++)
            KP[(mw + quad * 4 + r) * 264 + ni * 16 + col] = f2bf(acc[ni][r]);
    __syncthreads();
    f32x4 acc2[4] = {};
    const ushort* vp = vS + ((size_t)bl * 512 + h * 64) * 256;
#pragma unroll
    for (int ks = 0; ks < 8; ks++) {
        short8 a = *(const short8*)&KP[(mw + col) * 264 + ks * 32 + quad * 8];
#pragma unroll
        for (int ni = 0; ni < 4; ni++) {
            short8 bb = *(const short8*)&vp[(size_t)(ni * 16 + col) * 256 + ks * 32 + quad * 8];
            acc2[ni] = mfma_bf16(a, bb, acc2[ni]);
        }
    }
#pragma unroll
    for (int ni = 0; ni < 4; ni++)
#pragma unroll
        for (int r = 0; r < 4; r++) {
            int ml = mw + quad * 4 + r;
            float val = sat(acc2[ni][r] * rinv_[r], 64.f);
            outT[((size_t)bl * 1024 + m0 + ml) * 512 + h * 64 + ni * 16 + col] = f2bf(val);
        }
}

// ---------------------------------------------------------------------------
extern "C" void kernel_launch(void* const* d_in, const int* in_sizes, int n_in,
                              void* d_out, int out_size, void* d_ws, size_t ws_size,
                              hipStream_t stream) {
    const float* x   = (const float*)d_in[0];
    const float* Wq  = (const float*)d_in[1];
    const float* bq  = (const float*)d_in[2];
    const float* Wk  = (const float*)d_in[3];
    const float* bk  = (const float*)d_in[4];
    const float* Wv  = (const float*)d_in[5];
    const float* bv  = (const float*)d_in[6];
    const float* Wo  = (const float*)d_in[7];
    const float* bo  = (const float*)d_in[8];
    const float* dww = (const float*)d_in[9];
    const float* dwb = (const float*)d_in[10];
    const float* lng = (const float*)d_in[11];
    const float* lnb = (const float*)d_in[12];
    const float* pww = (const float*)d_in[13];
    const float* rpe = (const float*)d_in[14];
    float* out = (float*)d_out;

    char* wsb = (char*)d_ws;
    size_t off = 256;
    const size_t Wbf_bytes = (size_t)4 * 262144 * 2;   // 2 MB
    const size_t tb8_bytes = (size_t)8 * 4096 * 2;     // 64 KB
    ushort* Wbf = (ushort*)(wsb + off); off += Wbf_bytes;
    ushort* tb8 = (ushort*)(wsb + off); off += tb8_bytes;
    size_t base = (off + 255) & ~(size_t)255;

    const size_t xbT_b = (size_t)1024 * 512 * 2;   // 1 MB
    const size_t qT_b  = (size_t)1024 * 512 * 2;   // 1 MB
    const size_t xsT_b = (size_t)256 * 512 * 2;    // 256 KB
    const size_t kT_b  = (size_t)256 * 512 * 2;    // 256 KB
    const size_t vS_b  = (size_t)512 * 256 * 2;    // 256 KB
    const size_t oT_b  = (size_t)1024 * 512 * 2;   // 1 MB
    const size_t pos_b = (size_t)4 * 256 * 2 * 4;  // 8 KB
    const size_t per_b = xbT_b + qT_b + xsT_b + kT_b + vS_b + oT_b + pos_b + 1024;
    long long avail = (long long)ws_size - (long long)base;
    int bc_cap = (int)(avail > 0 ? avail / (long long)per_b : 0);
    if (bc_cap < 1) bc_cap = 1;
    if (bc_cap > 16) bc_cap = 16;

    prep_w<<<dim3(256, 4), 256, 0, stream>>>(Wq, Wk, Wv, Wo, Wbf);
    prep_rpe<<<8, 256, 0, stream>>>(rpe, tb8);
    const ushort* Wqb = Wbf;
    const ushort* Wkb = Wbf + 262144;
    const ushort* Wvb = Wbf + 2 * 262144;
    const ushort* Wob = Wbf + 3 * 262144;

    for (int b0 = 0; b0 < 16; b0 += bc_cap) {
        int bc = 16 - b0 < bc_cap ? 16 - b0 : bc_cap;
        char* p = wsb + base;
        ushort* xbT  = (ushort*)p; p += xbT_b * bc;
        ushort* qT   = (ushort*)p; p += qT_b * bc;
        ushort* xsT  = (ushort*)p; p += xsT_b * bc;
        ushort* kT   = (ushort*)p; p += kT_b * bc;
        ushort* vS   = (ushort*)p; p += vS_b * bc;
        ushort* outT = (ushort*)p; p += oT_b * bc;
        float*  pos  = (float*)p;

        prep_xT<<<dim3(32, 8, bc), 256, 0, stream>>>(x, xbT, b0);
        gemm128<1, 1><<<dim3(8, 4, bc), 256, 0, stream>>>(Wqb, xbT, bq, qT, 512,
                                                          (size_t)1024 * 512, (size_t)1024 * 512, 512, 0);
        offset_net<<<dim3(256, 4 * bc), 128, 0, stream>>>(qT, dww, dwb, lng, lnb, pww,
                                                          pos, out, b0);
        sample_x<<<dim3(256, 4 * bc), 128, 0, stream>>>(x, pos, xsT, b0);
        gemm128<1, 1><<<dim3(2, 4, bc), 256, 0, stream>>>(Wkb, xsT, bk, kT, 512,
                                                          (size_t)256 * 512, (size_t)256 * 512, 512, 0);
        gemm128<0, 1><<<dim3(2, 4, bc), 256, 0, stream>>>(Wvb, xsT, bv, vS, 512,
                                                          (size_t)256 * 512, (size_t)512 * 256, 256, 0);
        fused_attn<<<dim3(16, 8 * bc), 256, 0, stream>>>(qT, kT, vS, tb8, pos, outT);
        gemm128<0, 0><<<dim3(8, 4, bc), 256, 0, stream>>>(Wob, outT, bo, d_out, 512,
                                                          (size_t)1024 * 512, (size_t)512 * 1024, 1024,
                                                          (size_t)b0 * 512 * 1024);
    }
}

// Round 10
// 288.206 us; speedup vs baseline: 1.1549x; 1.1549x over previous
//
#include <hip/hip_runtime.h>

// Problem constants: B=16, NH=8, DH=64, NG=4, NC=512, CG=128, GH=2, H=W=32,
// HW=1024, Hs=Ws=16, NS=256, scale=0.125, ORF*off_range = 2/15.
// External buffers fp32; internal tensors bf16.

typedef __attribute__((ext_vector_type(8))) short short8;
typedef __attribute__((ext_vector_type(4))) float f32x4;

__device__ __forceinline__ float bf2f(ushort u) {
    union { uint i; float f; } c; c.i = ((uint)u) << 16; return c.f;
}
__device__ __forceinline__ ushort f2bf(float f) {
    union { float f; uint i; } c; c.f = f;
    uint x = c.i;
    return (ushort)((x + 0x7fffu + ((x >> 16) & 1u)) >> 16);  // RNE
}
__device__ __forceinline__ float sat(float v, float lim) {
    return fminf(fmaxf(v, -lim), lim);  // NaN-flushing clamp
}
__device__ __forceinline__ f32x4 mfma_bf16(short8 a, short8 b, f32x4 c) {
    return __builtin_amdgcn_mfma_f32_16x16x32_bf16(a, b, c, 0, 0, 0);
}

// ---------------------------------------------------------------------------
// One-time preps
__global__ __launch_bounds__(256) void prep_w(const float* __restrict__ w0,
                                              const float* __restrict__ w1,
                                              const float* __restrict__ w2,
                                              const float* __restrict__ w3,
                                              ushort* __restrict__ dst) {
    int widx = blockIdx.y;
    const float* src = widx == 0 ? w0 : widx == 1 ? w1 : widx == 2 ? w2 : w3;
    int i = blockIdx.x * 256 + threadIdx.x;
    float4 f = ((const float4*)src)[i];
    ushort4 u;
    u.x = f2bf(f.x); u.y = f2bf(f.y); u.z = f2bf(f.z); u.w = f2bf(f.w);
    ((ushort4*)(dst + (size_t)widx * 262144))[i] = u;
}

// rpe [8][63][63] fp32 -> padded bf16 [8][72][72]; valid at [4,66]^2, zeros outside.
__global__ __launch_bounds__(256) void prep_rpe(const float* __restrict__ rpe,
                                                ushort* __restrict__ tb8p) {
    int h = blockIdx.x, t = threadIdx.x;
    for (int i = t; i < 5184; i += 256) {
        int yy = i / 72, xx = i - yy * 72;
        int sy = yy - 4, sx = xx - 4;
        float v = ((unsigned)sy < 63u && (unsigned)sx < 63u)
                      ? rpe[(size_t)h * 3969 + sy * 63 + sx] : 0.f;
        tb8p[(size_t)h * 5184 + i] = f2bf(v);
    }
}

// x [b][512][1024] fp32 -> xbT [bl][1024][512] bf16 (transpose+convert)
__global__ __launch_bounds__(256) void prep_xT(const float* __restrict__ x,
                                               ushort* __restrict__ xbT, int b0) {
    __shared__ float tile[64][33];
    int n0 = blockIdx.x * 32, c0 = blockIdx.y * 64, bl = blockIdx.z, bg = b0 + bl;
    int t = threadIdx.x;
#pragma unroll
    for (int it = 0; it < 8; it++) {
        int cr = it * 8 + (t >> 5), col = t & 31;
        tile[cr][col] = x[((size_t)bg * 512 + c0 + cr) * 1024 + n0 + col];
    }
    __syncthreads();
#pragma unroll
    for (int it = 0; it < 8; it++) {
        int nr = it * 4 + (t >> 6), cc = t & 63;
        xbT[((size_t)bl * 1024 + n0 + nr) * 512 + c0 + cc] = f2bf(tile[cc][nr]);
    }
}

// ---------------------------------------------------------------------------
// 64x64-tile GEMM (for small-N k/v): C[m][n] = sum_k A[m][k]*B[n][k] + bias[m].
template <int OUT_T, int CINT>
__global__ __launch_bounds__(256) void gemm_tn(const ushort* __restrict__ A,
                                               const ushort* __restrict__ Bm,
                                               const float* __restrict__ bias,
                                               void* __restrict__ C, int K,
                                               size_t sB, size_t sC, int ldc, size_t c0) {
    __shared__ __align__(16) ushort As[64][72];
    __shared__ __align__(16) ushort Bs[64][72];
    int b = blockIdx.z, m0 = blockIdx.y * 64, n0 = blockIdx.x * 64;
    const ushort* Bp = Bm + (size_t)b * sB;
    size_t cb = c0 + (size_t)b * sC;
    int t = threadIdx.x, w = t >> 6, lane = t & 63, col = lane & 15, quad = lane >> 4;
    int m_off = (w & 1) * 32, n_off = (w >> 1) * 32;
    f32x4 acc[2][2] = {};
    for (int k0 = 0; k0 < K; k0 += 64) {
        __syncthreads();
        for (int i = t; i < 512; i += 256) {
            int r = i >> 3, c8 = (i & 7) * 8;
            *(uint4*)&As[r][c8] = *(const uint4*)&A[(size_t)(m0 + r) * K + k0 + c8];
            *(uint4*)&Bs[r][c8] = *(const uint4*)&Bp[(size_t)(n0 + r) * K + k0 + c8];
        }
        __syncthreads();
#pragma unroll
        for (int kk = 0; kk < 2; kk++) {
            short8 a0 = *(const short8*)&As[m_off + col][kk * 32 + quad * 8];
            short8 a1 = *(const short8*)&As[m_off + 16 + col][kk * 32 + quad * 8];
            short8 b0v = *(const short8*)&Bs[n_off + col][kk * 32 + quad * 8];
            short8 b1v = *(const short8*)&Bs[n_off + 16 + col][kk * 32 + quad * 8];
            acc[0][0] = mfma_bf16(a0, b0v, acc[0][0]);
            acc[0][1] = mfma_bf16(a0, b1v, acc[0][1]);
            acc[1][0] = mfma_bf16(a1, b0v, acc[1][0]);
            acc[1][1] = mfma_bf16(a1, b1v, acc[1][1]);
        }
    }
#pragma unroll
    for (int mi = 0; mi < 2; mi++)
#pragma unroll
        for (int ni = 0; ni < 2; ni++) {
            int mg = m0 + m_off + mi * 16 + quad * 4;
            int ng = n0 + n_off + ni * 16 + col;
            f32x4 vv = acc[mi][ni];
            if (OUT_T == 1) {
                ushort4 pk;
                pk.x = f2bf(sat(vv[0] + bias[mg + 0], 1e4f));
                pk.y = f2bf(sat(vv[1] + bias[mg + 1], 1e4f));
                pk.z = f2bf(sat(vv[2] + bias[mg + 2], 1e4f));
                pk.w = f2bf(sat(vv[3] + bias[mg + 3], 1e4f));
                *(ushort4*)&((ushort*)C)[cb + (size_t)ng * ldc + mg] = pk;
            } else {
#pragma unroll
                for (int r = 0; r < 4; r++) {
                    float v = sat(vv[r] + bias[mg + r], 1e4f);
                    if (CINT) ((ushort*)C)[cb + (size_t)(mg + r) * ldc + ng] = f2bf(v);
                    else ((float*)C)[cb + (size_t)(mg + r) * ldc + ng] = v;
                }
            }
        }
}

// ---------------------------------------------------------------------------
// 128x128-tile GEMM (for qx / Wo).
template <int OUT_T, int CINT>
__global__ __launch_bounds__(256) void gemm128(const ushort* __restrict__ A,
                                               const ushort* __restrict__ Bm,
                                               const float* __restrict__ bias,
                                               void* __restrict__ C, int K,
                                               size_t sB, size_t sC, int ldc, size_t c0) {
    __shared__ __align__(16) ushort As[128][72];
    __shared__ __align__(16) ushort Bs[128][72];
    int b = blockIdx.z, m0 = blockIdx.y * 128, n0 = blockIdx.x * 128;
    const ushort* Bp = Bm + (size_t)b * sB;
    size_t cb = c0 + (size_t)b * sC;
    int t = threadIdx.x, w = t >> 6, lane = t & 63, col = lane & 15, quad = lane >> 4;
    int m_off = (w & 1) * 64, n_off = (w >> 1) * 64;
    f32x4 acc[4][4] = {};
    for (int k0 = 0; k0 < K; k0 += 64) {
        __syncthreads();
        for (int i = t; i < 1024; i += 256) {
            int r = i >> 3, c8 = (i & 7) * 8;
            *(uint4*)&As[r][c8] = *(const uint4*)&A[(size_t)(m0 + r) * K + k0 + c8];
            *(uint4*)&Bs[r][c8] = *(const uint4*)&Bp[(size_t)(n0 + r) * K + k0 + c8];
        }
        __syncthreads();
#pragma unroll
        for (int kk = 0; kk < 2; kk++) {
            short8 af[4], bf[4];
#pragma unroll
            for (int mi = 0; mi < 4; mi++)
                af[mi] = *(const short8*)&As[m_off + mi * 16 + col][kk * 32 + quad * 8];
#pragma unroll
            for (int ni = 0; ni < 4; ni++)
                bf[ni] = *(const short8*)&Bs[n_off + ni * 16 + col][kk * 32 + quad * 8];
#pragma unroll
            for (int mi = 0; mi < 4; mi++)
#pragma unroll
                for (int ni = 0; ni < 4; ni++)
                    acc[mi][ni] = mfma_bf16(af[mi], bf[ni], acc[mi][ni]);
        }
    }
#pragma unroll
    for (int mi = 0; mi < 4; mi++)
#pragma unroll
        for (int ni = 0; ni < 4; ni++) {
            int mg = m0 + m_off + mi * 16 + quad * 4;
            int ng = n0 + n_off + ni * 16 + col;
            f32x4 vv = acc[mi][ni];
            if (OUT_T == 1) {
                ushort4 pk;
                pk.x = f2bf(sat(vv[0] + bias[mg + 0], 1e4f));
                pk.y = f2bf(sat(vv[1] + bias[mg + 1], 1e4f));
                pk.z = f2bf(sat(vv[2] + bias[mg + 2], 1e4f));
                pk.w = f2bf(sat(vv[3] + bias[mg + 3], 1e4f));
                *(ushort4*)&((ushort*)C)[cb + (size_t)ng * ldc + mg] = pk;
            } else {
#pragma unroll
                for (int r = 0; r < 4; r++) {
                    float v = sat(vv[r] + bias[mg + r], 1e4f);
                    if (CINT) ((ushort*)C)[cb + (size_t)(mg + r) * ldc + ng] = f2bf(v);
                    else ((float*)C)[cb + (size_t)(mg + r) * ldc + ng] = v;
                }
            }
        }
}

// ---------------------------------------------------------------------------
// Offset network, single-wave: depthwise 3x3 s2 p1 -> LN -> GELU -> 1x1 -> tanh.
// 64 threads, 2 channels each; all reductions via wave shuffles (no barriers).
__global__ __launch_bounds__(64) void offset_net(
    const ushort* __restrict__ qT, const float* __restrict__ dww,
    const float* __restrict__ dwb, const float* __restrict__ lng,
    const float* __restrict__ lnb, const float* __restrict__ pww,
    float* __restrict__ pos, float* __restrict__ out, int b0) {
    int n = blockIdx.y, sp = blockIdx.x, bl = n >> 2, bg = b0 + bl, g = n & 3;
    int i = sp >> 4, j = sp & 15, lane = threadIdx.x;
    int c0 = lane, c1 = lane + 64;
    float a0 = dwb[c0], a1 = dwb[c1];
#pragma unroll
    for (int dy = 0; dy < 3; dy++) {
        int yy = 2 * i - 1 + dy;
        if (yy < 0 || yy > 31) continue;
#pragma unroll
        for (int dx = 0; dx < 3; dx++) {
            int xx = 2 * j - 1 + dx;
            if (xx < 0 || xx > 31) continue;
            const ushort* qrow = qT + ((size_t)bl * 1024 + yy * 32 + xx) * 512 + g * 128;
            a0 += dww[c0 * 9 + dy * 3 + dx] * bf2f(qrow[c0]);
            a1 += dww[c1 * 9 + dy * 3 + dx] * bf2f(qrow[c1]);
        }
    }
    float s = a0 + a1, s2 = a0 * a0 + a1 * a1;
#pragma unroll
    for (int off = 1; off < 64; off <<= 1) {
        s += __shfl_xor(s, off);
        s2 += __shfl_xor(s2, off);
    }
    float mu = s * (1.f / 128.f);
    float var = s2 * (1.f / 128.f) - mu * mu;
    float rstd = rsqrtf(fmaxf(var, 0.f) + 1e-5f);
    float g0 = (a0 - mu) * rstd * lng[c0] + lnb[c0];
    float g1 = (a1 - mu) * rstd * lng[c1] + lnb[c1];
    g0 = 0.5f * g0 * (1.f + erff(g0 * 0.70710678118654752f));
    g1 = 0.5f * g1 * (1.f + erff(g1 * 0.70710678118654752f));
    float p0 = g0 * pww[c0] + g1 * pww[c1];
    float p1 = g0 * pww[128 + c0] + g1 * pww[128 + c1];
#pragma unroll
    for (int off = 1; off < 64; off <<= 1) {
        p0 += __shfl_xor(p0, off);
        p1 += __shfl_xor(p1, off);
    }
    if (lane == 0) {
        float offy = tanhf(p0) * (2.f / 15.f);
        float offx = tanhf(p1) * (2.f / 15.f);
        float ry = ((float)i + 0.5f) * (2.f / 15.f) - 1.f;
        float rx = ((float)j + 0.5f) * (2.f / 15.f) - 1.f;
        float py = sat(offy + ry, 1.2f), px = sat(offx + rx, 1.2f);
        size_t ol = ((size_t)(bl * 4 + g) * 256 + sp) * 2;   // chunk-local
        pos[ol] = py; pos[ol + 1] = px;
        size_t og = ((size_t)(bg * 4 + g) * 256 + sp) * 2;   // global out offset
        out[8388608 + og] = py;  out[8388608 + og + 1] = px;
        out[8421376 + og] = ry;  out[8421376 + og + 1] = rx;
    }
}

// ---------------------------------------------------------------------------
// Bilinear sample from xbT (bf16, channel-contiguous) -> xsT[bl][s][512].
__global__ __launch_bounds__(128) void sample_x(const ushort* __restrict__ xbT,
                                                const float* __restrict__ pos,
                                                ushort* __restrict__ xsT) {
    int nl = blockIdx.y, s = blockIdx.x, bl = nl >> 2, g = nl & 3, c = threadIdx.x;
    size_t po = ((size_t)(bl * 4 + g) * 256 + s) * 2;
    float py = pos[po], px = pos[po + 1];
    float gx = (px + 1.f) * 15.5f;
    float gy = (py + 1.f) * 15.5f;
    float x0f = floorf(gx), y0f = floorf(gy);
    int ix0 = (int)x0f, iy0 = (int)y0f;
    float wx1 = gx - x0f, wx0 = 1.f - wx1, wy1 = gy - y0f, wy0 = 1.f - wy1;
    const ushort* xb = xbT + (size_t)bl * 1024 * 512 + g * 128 + c;
    float acc = 0.f;
#define CORNER(ix, iy, wgt)                                            \
    if ((unsigned)(ix) < 32u && (unsigned)(iy) < 32u)                  \
        acc += (wgt) * bf2f(xb[(size_t)((iy) * 32 + (ix)) * 512]);
    CORNER(ix0, iy0, wx0 * wy0)
    CORNER(ix0 + 1, iy0, wx1 * wy0)
    CORNER(ix0, iy0 + 1, wx0 * wy1)
    CORNER(ix0 + 1, iy0 + 1, wx1 * wy1)
#undef CORNER
    xsT[((size_t)bl * 256 + s) * 512 + g * 128 + c] = f2bf(sat(acc, 64.f));
}

// ---------------------------------------------------------------------------
// Fused attention v4: padded 72x72 table (no clamps), per-s base indices,
// K in LDS (union with P), in-register softmax.
__global__ __launch_bounds__(256, 2) void fused_attn(const ushort* __restrict__ qT,
                                                     const ushort* __restrict__ kT,
                                                     const ushort* __restrict__ vS,
                                                     const ushort* __restrict__ tb8p,
                                                     const float* __restrict__ pos,
                                                     ushort* __restrict__ outT) {
    __shared__ __align__(16) ushort KP[256 * 72];  // K phase: Ks[s][72]; P phase: Pl[m*264+s]
    __shared__ __align__(16) ushort Tbp[5184];     // 72x72 padded table
    __shared__ float4 sW4[256];
    __shared__ int sBase[256];
    int bh = blockIdx.y, bl = bh >> 3, h = bh & 7, g = h >> 1;
    int m0 = blockIdx.x * 64;
    int t = threadIdx.x;
    {
        const ushort* kb = kT + (size_t)bl * 256 * 512 + h * 64;
        for (int i = t; i < 2048; i += 256) {
            int s = i >> 3, part = i & 7;
            *(uint4*)&KP[s * 72 + part * 8] = *(const uint4*)&kb[(size_t)s * 512 + part * 8];
        }
    }
    // 5184 ushorts = 648 uint4 (fixed from 324: half-staged table was the R9 bug)
    for (int i = t; i < 648; i += 256)
        ((uint4*)Tbp)[i] = ((const uint4*)(tb8p + (size_t)h * 5184))[i];
    {
        int s = t;
        float psy = pos[(size_t)(bl * 4 + g) * 512 + 2 * s];
        float psx = pos[(size_t)(bl * 4 + g) * 512 + 2 * s + 1];
        float syf = 15.5f - 15.5f * psy;
        float sxf = 15.5f - 15.5f * psx;
        float fy = floorf(syf), fx = floorf(sxf);
        float wy1 = syf - fy, wy0 = 1.f - wy1;
        float wx1 = sxf - fx, wx0 = 1.f - wx1;
        sBase[s] = ((int)fy + 4) * 72 + (int)fx + 4;
        sW4[s] = make_float4(wx0 * wy0, wx1 * wy0, wx0 * wy1, wx1 * wy1);
    }
    __syncthreads();
    int w = t >> 6, lane = t & 63, col = lane & 15, quad = lane >> 4;
    int mw = w * 16;
    const ushort* qrow = qT + ((size_t)bl * 1024 + m0 + mw + col) * 512 + h * 64;
    short8 a0 = *(const short8*)&qrow[quad * 8];
    short8 a1 = *(const short8*)&qrow[32 + quad * 8];
    f32x4 acc[16] = {};
#pragma unroll
    for (int ni = 0; ni < 16; ni++) {
        short8 b0v = *(const short8*)&KP[(ni * 16 + col) * 72 + quad * 8];
        short8 b1v = *(const short8*)&KP[(ni * 16 + col) * 72 + 32 + quad * 8];
        acc[ni] = mfma_bf16(a0, b0v, acc[ni]);
        acc[ni] = mfma_bf16(a1, b1v, acc[ni]);
    }
    // epilogue: logits = acc*scale + rpe bias; all indices provably in-range
    int mbase = m0 + mw;
    int cw = (mbase >> 5) * 72 + (mbase & 31) + quad * 4;  // wave/thread const
#pragma unroll
    for (int ni = 0; ni < 16; ni++) {
        int s = ni * 16 + col;
        int base = sBase[s] + cw;
        float4 w4 = sW4[s];
        float t0[5], t1[5];
#pragma unroll
        for (int jj = 0; jj < 5; jj++) {
            t0[jj] = bf2f(Tbp[base + jj]);
            t1[jj] = bf2f(Tbp[base + 72 + jj]);
        }
#pragma unroll
        for (int r = 0; r < 4; r++) {
            float bias = w4.x * t0[r] + w4.y * t0[r + 1] + w4.z * t1[r] + w4.w * t1[r + 1];
            acc[ni][r] = sat(acc[ni][r] * 0.125f + bias, 64.f);
        }
    }
    float rinv_[4];
#pragma unroll
    for (int r = 0; r < 4; r++) {
        float mr = acc[0][r];
#pragma unroll
        for (int ni = 1; ni < 16; ni++) mr = fmaxf(mr, acc[ni][r]);
#pragma unroll
        for (int off = 1; off < 16; off <<= 1) mr = fmaxf(mr, __shfl_xor(mr, off));
        float sr = 0.f;
#pragma unroll
        for (int ni = 0; ni < 16; ni++) {
            float e = __expf(acc[ni][r] - mr);
            acc[ni][r] = e;
            sr += e;
        }
#pragma unroll
        for (int off = 1; off < 16; off <<= 1) sr += __shfl_xor(sr, off);
        rinv_[r] = 1.f / sr;
    }
    __syncthreads();
#pragma unroll
    for (int ni = 0; ni < 16; ni++)
#pragma unroll
        for (int r = 0; r < 4; r++)
            KP[(mw + quad * 4 + r) * 264 + ni * 16 + col] = f2bf(acc[ni][r]);
    __syncthreads();
    f32x4 acc2[4] = {};
    const ushort* vp = vS + ((size_t)bl * 512 + h * 64) * 256;
#pragma unroll
    for (int ks = 0; ks < 8; ks++) {
        short8 a = *(const short8*)&KP[(mw + col) * 264 + ks * 32 + quad * 8];
#pragma unroll
        for (int ni = 0; ni < 4; ni++) {
            short8 bb = *(const short8*)&vp[(size_t)(ni * 16 + col) * 256 + ks * 32 + quad * 8];
            acc2[ni] = mfma_bf16(a, bb, acc2[ni]);
        }
    }
#pragma unroll
    for (int ni = 0; ni < 4; ni++)
#pragma unroll
        for (int r = 0; r < 4; r++) {
            int ml = mw + quad * 4 + r;
            float val = sat(acc2[ni][r] * rinv_[r], 64.f);
            outT[((size_t)bl * 1024 + m0 + ml) * 512 + h * 64 + ni * 16 + col] = f2bf(val);
        }
}

// ---------------------------------------------------------------------------
extern "C" void kernel_launch(void* const* d_in, const int* in_sizes, int n_in,
                              void* d_out, int out_size, void* d_ws, size_t ws_size,
                              hipStream_t stream) {
    const float* x   = (const float*)d_in[0];
    const float* Wq  = (const float*)d_in[1];
    const float* bq  = (const float*)d_in[2];
    const float* Wk  = (const float*)d_in[3];
    const float* bk  = (const float*)d_in[4];
    const float* Wv  = (const float*)d_in[5];
    const float* bv  = (const float*)d_in[6];
    const float* Wo  = (const float*)d_in[7];
    const float* bo  = (const float*)d_in[8];
    const float* dww = (const float*)d_in[9];
    const float* dwb = (const float*)d_in[10];
    const float* lng = (const float*)d_in[11];
    const float* lnb = (const float*)d_in[12];
    const float* pww = (const float*)d_in[13];
    const float* rpe = (const float*)d_in[14];
    float* out = (float*)d_out;

    char* wsb = (char*)d_ws;
    size_t off = 256;
    const size_t Wbf_bytes  = (size_t)4 * 262144 * 2;  // 2 MB
    const size_t tb8p_bytes = (size_t)8 * 5184 * 2;    // ~83 KB
    ushort* Wbf  = (ushort*)(wsb + off); off += Wbf_bytes;
    ushort* tb8p = (ushort*)(wsb + off); off += tb8p_bytes;
    size_t base = (off + 255) & ~(size_t)255;

    const size_t xbT_b = (size_t)1024 * 512 * 2;   // 1 MB
    const size_t qT_b  = (size_t)1024 * 512 * 2;   // 1 MB
    const size_t xsT_b = (size_t)256 * 512 * 2;    // 256 KB
    const size_t kT_b  = (size_t)256 * 512 * 2;    // 256 KB
    const size_t vS_b  = (size_t)512 * 256 * 2;    // 256 KB
    const size_t oT_b  = (size_t)1024 * 512 * 2;   // 1 MB
    const size_t pos_b = (size_t)4 * 256 * 2 * 4;  // 8 KB
    const size_t per_b = xbT_b + qT_b + xsT_b + kT_b + vS_b + oT_b + pos_b + 1024;
    long long avail = (long long)ws_size - (long long)base;
    int bc_cap = (int)(avail > 0 ? avail / (long long)per_b : 0);
    if (bc_cap < 1) bc_cap = 1;
    if (bc_cap > 16) bc_cap = 16;

    prep_w<<<dim3(256, 4), 256, 0, stream>>>(Wq, Wk, Wv, Wo, Wbf);
    prep_rpe<<<8, 256, 0, stream>>>(rpe, tb8p);
    const ushort* Wqb = Wbf;
    const ushort* Wkb = Wbf + 262144;
    const ushort* Wvb = Wbf + 2 * 262144;
    const ushort* Wob = Wbf + 3 * 262144;

    for (int b0 = 0; b0 < 16; b0 += bc_cap) {
        int bc = 16 - b0 < bc_cap ? 16 - b0 : bc_cap;
        char* p = wsb + base;
        ushort* xbT  = (ushort*)p; p += xbT_b * bc;
        ushort* qT   = (ushort*)p; p += qT_b * bc;
        ushort* xsT  = (ushort*)p; p += xsT_b * bc;
        ushort* kT   = (ushort*)p; p += kT_b * bc;
        ushort* vS   = (ushort*)p; p += vS_b * bc;
        ushort* outT = (ushort*)p; p += oT_b * bc;
        float*  pos  = (float*)p;

        prep_xT<<<dim3(32, 8, bc), 256, 0, stream>>>(x, xbT, b0);
        gemm128<1, 1><<<dim3(8, 4, bc), 256, 0, stream>>>(Wqb, xbT, bq, qT, 512,
                                                          (size_t)1024 * 512, (size_t)1024 * 512, 512, 0);
        offset_net<<<dim3(256, 4 * bc), 64, 0, stream>>>(qT, dww, dwb, lng, lnb, pww,
                                                         pos, out, b0);
        sample_x<<<dim3(256, 4 * bc), 128, 0, stream>>>(xbT, pos, xsT);
        gemm_tn<1, 1><<<dim3(4, 8, bc), 256, 0, stream>>>(Wkb, xsT, bk, kT, 512,
                                                          (size_t)256 * 512, (size_t)256 * 512, 512, 0);
        gemm_tn<0, 1><<<dim3(4, 8, bc), 256, 0, stream>>>(Wvb, xsT, bv, vS, 512,
                                                          (size_t)256 * 512, (size_t)512 * 256, 256, 0);
        fused_attn<<<dim3(16, 8 * bc), 256, 0, stream>>>(qT, kT, vS, tb8p, pos, outT);
        gemm128<0, 0><<<dim3(8, 4, bc), 256, 0, stream>>>(Wob, outT, bo, d_out, 512,
                                                          (size_t)1024 * 512, (size_t)512 * 1024, 1024,
                                                          (size_t)b0 * 512 * 1024);
    }
}